// Round 1
// baseline (2230.688 us; speedup 1.0000x reference)
//
#include <hip/hip_runtime.h>
#include <hip/hip_bf16.h>
#include <math.h>

constexpr int Bx = 4, Lx = 1024, DM = 512, DS = 16, NL = 4, EDx = 1024;
constexpr int DTR = 32;

// ---------------- x = seq @ Wi^T + bi ----------------
__global__ __launch_bounds__(256) void k_init_x(const float* __restrict__ seq,
    const float* __restrict__ Wi, const float* __restrict__ bi, float* __restrict__ x) {
  int idx = blockIdx.x * 256 + threadIdx.x;      // over B*L*DM
  int d = idx & (DM - 1);
  int bl = idx >> 9;
  float s0 = seq[bl * 3 + 0], s1 = seq[bl * 3 + 1], s2 = seq[bl * 3 + 2];
  x[idx] = bi[d] + s0 * Wi[d * 3 + 0] + s1 * Wi[d * 3 + 1] + s2 * Wi[d * 3 + 2];
}

// ---------------- generic fp32 GEMM: C[M,N] = A[M,lda(K)] @ W[N,ldw(K)]^T ----------------
// EPI: 0 = none, 1 = softplus(v + bias[n])
template <int BM, int BN, int EPI>
__global__ __launch_bounds__(256) void k_gemm_tn(
    const float* __restrict__ A, int lda,
    const float* __restrict__ W, int ldw,
    const float* __restrict__ bias,
    float* __restrict__ C, int ldc, int K) {
  constexpr int BK = 16;
  constexpr int MR = BM / 16, NR = BN / 16;
  __shared__ float As[BK][BM + 4];
  __shared__ float Bs[BK][BN + 4];
  const int tid = threadIdx.x;
  const int tx = tid & 15, ty = tid >> 4;
  const int m0 = blockIdx.x * BM, n0 = blockIdx.y * BN;
  const int arow = tid >> 2;           // 0..63
  const int akol = (tid & 3) << 2;     // 0,4,8,12
  float acc[MR][NR] = {};
  for (int k0 = 0; k0 < K; k0 += BK) {
    #pragma unroll
    for (int r = 0; r < BM / 64; ++r) {
      int m = arow + r * 64;
      const float4 v = *(const float4*)(A + (size_t)(m0 + m) * lda + k0 + akol);
      As[akol + 0][m] = v.x; As[akol + 1][m] = v.y;
      As[akol + 2][m] = v.z; As[akol + 3][m] = v.w;
    }
    if constexpr (BN >= 64) {
      #pragma unroll
      for (int r = 0; r < BN / 64; ++r) {
        int n = arow + r * 64;
        const float4 v = *(const float4*)(W + (size_t)(n0 + n) * ldw + k0 + akol);
        Bs[akol + 0][n] = v.x; Bs[akol + 1][n] = v.y;
        Bs[akol + 2][n] = v.z; Bs[akol + 3][n] = v.w;
      }
    } else {
      if (arow < BN) {
        const float4 v = *(const float4*)(W + (size_t)(n0 + arow) * ldw + k0 + akol);
        Bs[akol + 0][arow] = v.x; Bs[akol + 1][arow] = v.y;
        Bs[akol + 2][arow] = v.z; Bs[akol + 3][arow] = v.w;
      }
    }
    __syncthreads();
    #pragma unroll
    for (int k = 0; k < BK; ++k) {
      float af[MR], bf[NR];
      #pragma unroll
      for (int i = 0; i < MR; ++i) af[i] = As[k][ty * MR + i];
      #pragma unroll
      for (int j = 0; j < NR; ++j) bf[j] = Bs[k][tx * NR + j];
      #pragma unroll
      for (int i = 0; i < MR; ++i)
        #pragma unroll
        for (int j = 0; j < NR; ++j)
          acc[i][j] = fmaf(af[i], bf[j], acc[i][j]);
    }
    __syncthreads();
  }
  #pragma unroll
  for (int i = 0; i < MR; ++i) {
    int m = m0 + ty * MR + i;
    #pragma unroll
    for (int j = 0; j < NR; ++j) {
      int n = n0 + tx * NR + j;
      float v = acc[i][j];
      if constexpr (EPI == 1) {
        v += bias[n];
        v = (v > 20.f) ? v : log1pf(__expf(v));
      }
      C[(size_t)m * ldc + n] = v;
    }
  }
}

// ---------------- causal depthwise conv (D_CONV=4) + bias + silu ----------------
__global__ __launch_bounds__(256) void k_conv_silu(const float* __restrict__ xz,
    const float* __restrict__ cw, const float* __restrict__ cb, float* __restrict__ xb) {
  int idx = blockIdx.x * 256 + threadIdx.x;    // over B*L*ED
  int e = idx & (EDx - 1);
  int bl = idx >> 10;                          // b*L + l
  int l = bl & (Lx - 1);
  const float4 w = ((const float4*)cw)[e];
  float acc = cb[e];
  if (l - 3 >= 0) acc = fmaf(xz[(size_t)(bl - 3) * (2 * EDx) + e], w.x, acc);
  if (l - 2 >= 0) acc = fmaf(xz[(size_t)(bl - 2) * (2 * EDx) + e], w.y, acc);
  if (l - 1 >= 0) acc = fmaf(xz[(size_t)(bl - 1) * (2 * EDx) + e], w.z, acc);
  acc = fmaf(xz[(size_t)bl * (2 * EDx) + e], w.w, acc);
  xb[idx] = acc / (1.f + __expf(-acc));
}

// ---------------- selective scan, fused y = (sum_n h*C + D*xb) * silu(z) ----------------
// 16 chains per block (16 consecutive e, same b), 16 lanes per chain (lane = state n).
__global__ __launch_bounds__(256) void k_scan(
    float* __restrict__ dy,                 // in: delta  /  out: y   (in-place)
    const float* __restrict__ xb,
    const float* __restrict__ dbc,          // [B*L][64], B at +32, C at +48
    const float* __restrict__ xz,           // z at column offset ED
    const float* __restrict__ Alog,
    const float* __restrict__ Dp) {
  __shared__ float d_s[64][16], xb_s[64][16], z_s[64][16], bc_s[64][32], y_s[64][16];
  const int tid = threadIdx.x;
  const int g = tid >> 4, n = tid & 15;
  const int chain = blockIdx.x * 16 + g;
  const int b = chain >> 10;
  const int e = chain & (EDx - 1);
  const int e0 = (blockIdx.x * 16) & (EDx - 1);
  const float Aen = -__expf(Alog[e * DS + n]);
  const float De = Dp[e];
  const size_t bl0 = (size_t)b * Lx;
  float h = 0.f;
  for (int lc = 0; lc < Lx; lc += 64) {
    __syncthreads();
    #pragma unroll
    for (int r = 0; r < 4; ++r) {
      int i = r * 16 + g;
      size_t gi = (bl0 + lc + i) * (size_t)EDx + e0 + n;
      d_s[i][n] = dy[gi];
      xb_s[i][n] = xb[gi];
      z_s[i][n] = xz[(bl0 + lc + i) * (size_t)(2 * EDx) + EDx + e0 + n];
    }
    {
      const int j2 = tid & 31;
      #pragma unroll
      for (int r = 0; r < 8; ++r) {
        int i = r * 8 + (tid >> 5);
        bc_s[i][j2] = dbc[(bl0 + lc + i) * 64 + 32 + j2];
      }
    }
    __syncthreads();
    #pragma unroll 4
    for (int i = 0; i < 64; ++i) {
      float dl = d_s[i][g];
      float xbl = xb_s[i][g];
      float dA = __expf(dl * Aen);
      float dBx = dl * xbl * bc_s[i][n];
      h = fmaf(dA, h, dBx);
      float p = h * bc_s[i][16 + n];
      p += __shfl_xor(p, 8);
      p += __shfl_xor(p, 4);
      p += __shfl_xor(p, 2);
      p += __shfl_xor(p, 1);
      if (n == 0) {
        float zv = z_s[i][g];
        float sz = zv / (1.f + __expf(-zv));
        y_s[i][g] = (p + De * xbl) * sz;
      }
    }
    __syncthreads();
    #pragma unroll
    for (int r = 0; r < 4; ++r) {
      int i = r * 16 + g;
      dy[(bl0 + lc + i) * (size_t)EDx + e0 + n] = y_s[i][n];
    }
  }
}

// ---------------- last-token LayerNorm + head ----------------
__global__ __launch_bounds__(256) void k_ln_head(
    const float* __restrict__ x, const float* __restrict__ g,
    const float* __restrict__ be, const float* __restrict__ Wo,
    const float* __restrict__ bo, float* __restrict__ out) {
  const int b = blockIdx.x;
  const int t = threadIdx.x;
  const float* xr = x + ((size_t)b * Lx + (Lx - 1)) * DM;
  __shared__ float w1[4], w2[4];
  __shared__ float xn[DM];
  __shared__ float hp[20][8];
  float a0 = xr[t], a1 = xr[t + 256];
  float p = a0 + a1;
  #pragma unroll
  for (int o = 32; o > 0; o >>= 1) p += __shfl_down(p, o);
  if ((t & 63) == 0) w1[t >> 6] = p;
  __syncthreads();
  float mean = (w1[0] + w1[1] + w1[2] + w1[3]) * (1.f / DM);
  float d0 = a0 - mean, d1 = a1 - mean;
  p = d0 * d0 + d1 * d1;
  #pragma unroll
  for (int o = 32; o > 0; o >>= 1) p += __shfl_down(p, o);
  if ((t & 63) == 0) w2[t >> 6] = p;
  __syncthreads();
  float rstd = rsqrtf((w2[0] + w2[1] + w2[2] + w2[3]) * (1.f / DM) + 1e-5f);
  xn[t] = d0 * rstd * g[t] + be[t];
  xn[t + 256] = d1 * rstd * g[t + 256] + be[t + 256];
  __syncthreads();
  if (t < 160) {
    int j = t / 8, sg = t % 8;
    const float* wr = Wo + (size_t)j * DM + sg * 64;
    const float* xs = xn + sg * 64;
    float s = 0.f;
    #pragma unroll
    for (int k = 0; k < 64; ++k) s = fmaf(xs[k], wr[k], s);
    hp[j][sg] = s;
  }
  __syncthreads();
  if (t < 20) {
    float s = bo[t];
    #pragma unroll
    for (int k = 0; k < 8; ++k) s += hp[t][k];
    out[b * 20 + t] = s;
  }
}

extern "C" void kernel_launch(void* const* d_in, const int* in_sizes, int n_in,
                              void* d_out, int out_size, void* d_ws, size_t ws_size,
                              hipStream_t stream) {
  (void)in_sizes; (void)n_in; (void)out_size; (void)ws_size;
  const float* seq    = (const float*)d_in[0];
  const float* Wi     = (const float*)d_in[1];
  const float* bi     = (const float*)d_in[2];
  const float* Wo     = (const float*)d_in[3];
  const float* bo     = (const float*)d_in[4];
  const float* ln_g   = (const float*)d_in[5];
  const float* ln_b   = (const float*)d_in[6];
  const float* lWin   = (const float*)d_in[7];
  const float* lconvw = (const float*)d_in[8];
  const float* lconvb = (const float*)d_in[9];
  const float* lWx    = (const float*)d_in[10];
  const float* lWdt   = (const float*)d_in[11];
  const float* lbdt   = (const float*)d_in[12];
  const float* lAlog  = (const float*)d_in[13];
  const float* lD     = (const float*)d_in[14];
  const float* lWout  = (const float*)d_in[15];

  float* ws  = (float*)d_ws;
  float* X   = ws;                 // [4096][512]   = 2M floats
  float* XZ  = X + 2097152;        // [4096][2048]  = 8M floats
  float* XB  = XZ + 8388608;       // [4096][1024]  = 4M floats
  float* DBC = XB + 4194304;       // [4096][64]    = 256K floats
  float* DEL = DBC + 262144;       // [4096][1024]  = 4M floats (delta, then y in-place)

  k_init_x<<<dim3(Bx * Lx * DM / 256), 256, 0, stream>>>(seq, Wi, bi, X);

  for (int i = 0; i < NL; ++i) {
    const float* Win  = lWin   + (size_t)i * 2048 * 512;
    const float* cw   = lconvw + (size_t)i * EDx * 4;
    const float* cb   = lconvb + (size_t)i * EDx;
    const float* Wx   = lWx    + (size_t)i * 64 * EDx;
    const float* Wdt  = lWdt   + (size_t)i * EDx * DTR;
    const float* bdt  = lbdt   + (size_t)i * EDx;
    const float* Alog = lAlog  + (size_t)i * EDx * DS;
    const float* Dp   = lD     + (size_t)i * EDx;
    const float* Wout = lWout  + (size_t)i * DM * EDx;

    // xz = x @ Win^T            [4096,2048] K=512
    k_gemm_tn<128, 128, 0><<<dim3(32, 16), 256, 0, stream>>>(X, DM, Win, DM, nullptr, XZ, 2 * EDx, DM);
    // xb = silu(causal_dwconv(xz[:, :ED]) + cb)
    k_conv_silu<<<dim3(Bx * Lx * EDx / 256), 256, 0, stream>>>(XZ, cw, cb, XB);
    // dbc = xb @ Wx^T           [4096,64] K=1024
    k_gemm_tn<64, 16, 0><<<dim3(64, 4), 256, 0, stream>>>(XB, EDx, Wx, EDx, nullptr, DBC, 64, EDx);
    // delta = softplus(dbc[:, :32] @ Wdt^T + bdt)   [4096,1024] K=32
    k_gemm_tn<128, 64, 1><<<dim3(32, 16), 256, 0, stream>>>(DBC, 64, Wdt, DTR, bdt, DEL, EDx, DTR);
    // selective scan + gating, y written over DEL
    k_scan<<<dim3(256), 256, 0, stream>>>(DEL, XB, DBC, XZ, Alog, Dp);
    // x = y @ Wout^T            [4096,512] K=1024
    k_gemm_tn<128, 64, 0><<<dim3(32, 8), 256, 0, stream>>>(DEL, EDx, Wout, EDx, nullptr, X, DM, EDx);
  }

  k_ln_head<<<dim3(Bx), 256, 0, stream>>>(X, ln_g, ln_b, Wo, bo, (float*)d_out);
}

// Round 4
// 1651.396 us; speedup vs baseline: 1.3508x; 1.3508x over previous
//
#include <hip/hip_runtime.h>
#include <hip/hip_bf16.h>
#include <math.h>

constexpr int Bx = 4, Lx = 1024, DM = 512, DS = 16, NL = 4, EDx = 1024;
constexpr int DTR = 32;
constexpr int NC = 32, CT = Lx / NC;   // 32 chunks x 32 steps

// ---------------- x = seq @ Wi^T + bi ----------------
__global__ __launch_bounds__(256) void k_init_x(const float* __restrict__ seq,
    const float* __restrict__ Wi, const float* __restrict__ bi, float* __restrict__ x) {
  int idx = blockIdx.x * 256 + threadIdx.x;      // over B*L*DM
  int d = idx & (DM - 1);
  int bl = idx >> 9;
  float s0 = seq[bl * 3 + 0], s1 = seq[bl * 3 + 1], s2 = seq[bl * 3 + 2];
  x[idx] = bi[d] + s0 * Wi[d * 3 + 0] + s1 * Wi[d * 3 + 1] + s2 * Wi[d * 3 + 2];
}

// ---------------- generic fp32 GEMM: C[M,N] = A[M,lda(K)] @ W[N,ldw(K)]^T ----------------
template <int BM, int BN, int EPI>
__global__ __launch_bounds__(256) void k_gemm_tn(
    const float* __restrict__ A, int lda,
    const float* __restrict__ W, int ldw,
    const float* __restrict__ bias,
    float* __restrict__ C, int ldc, int K) {
  constexpr int BK = 16;
  constexpr int MR = BM / 16, NR = BN / 16;
  __shared__ float As[BK][BM + 4];
  __shared__ float Bs[BK][BN + 4];
  const int tid = threadIdx.x;
  const int tx = tid & 15, ty = tid >> 4;
  const int m0 = blockIdx.x * BM, n0 = blockIdx.y * BN;
  const int arow = tid >> 2;           // 0..63
  const int akol = (tid & 3) << 2;     // 0,4,8,12
  float acc[MR][NR] = {};
  for (int k0 = 0; k0 < K; k0 += BK) {
    #pragma unroll
    for (int r = 0; r < BM / 64; ++r) {
      int m = arow + r * 64;
      const float4 v = *(const float4*)(A + (size_t)(m0 + m) * lda + k0 + akol);
      As[akol + 0][m] = v.x; As[akol + 1][m] = v.y;
      As[akol + 2][m] = v.z; As[akol + 3][m] = v.w;
    }
    if constexpr (BN >= 64) {
      #pragma unroll
      for (int r = 0; r < BN / 64; ++r) {
        int n = arow + r * 64;
        const float4 v = *(const float4*)(W + (size_t)(n0 + n) * ldw + k0 + akol);
        Bs[akol + 0][n] = v.x; Bs[akol + 1][n] = v.y;
        Bs[akol + 2][n] = v.z; Bs[akol + 3][n] = v.w;
      }
    } else {
      if (arow < BN) {
        const float4 v = *(const float4*)(W + (size_t)(n0 + arow) * ldw + k0 + akol);
        Bs[akol + 0][arow] = v.x; Bs[akol + 1][arow] = v.y;
        Bs[akol + 2][arow] = v.z; Bs[akol + 3][arow] = v.w;
      }
    }
    __syncthreads();
    #pragma unroll
    for (int k = 0; k < BK; ++k) {
      float af[MR], bf[NR];
      #pragma unroll
      for (int i = 0; i < MR; ++i) af[i] = As[k][ty * MR + i];
      #pragma unroll
      for (int j = 0; j < NR; ++j) bf[j] = Bs[k][tx * NR + j];
      #pragma unroll
      for (int i = 0; i < MR; ++i)
        #pragma unroll
        for (int j = 0; j < NR; ++j)
          acc[i][j] = fmaf(af[i], bf[j], acc[i][j]);
    }
    __syncthreads();
  }
  #pragma unroll
  for (int i = 0; i < MR; ++i) {
    int m = m0 + ty * MR + i;
    #pragma unroll
    for (int j = 0; j < NR; ++j) {
      int n = n0 + tx * NR + j;
      float v = acc[i][j];
      if constexpr (EPI == 1) {
        v += bias[n];
        v = (v > 20.f) ? v : log1pf(__expf(v));
      }
      C[(size_t)m * ldc + n] = v;
    }
  }
}

// ---------------- causal depthwise conv (D_CONV=4) + bias + silu ----------------
__global__ __launch_bounds__(256) void k_conv_silu(const float* __restrict__ xz,
    const float* __restrict__ cw, const float* __restrict__ cb, float* __restrict__ xb) {
  int idx = blockIdx.x * 256 + threadIdx.x;    // over B*L*ED
  int e = idx & (EDx - 1);
  int bl = idx >> 10;                          // b*L + l
  int l = bl & (Lx - 1);
  const float4 w = ((const float4*)cw)[e];
  float acc = cb[e];
  if (l - 3 >= 0) acc = fmaf(xz[(size_t)(bl - 3) * (2 * EDx) + e], w.x, acc);
  if (l - 2 >= 0) acc = fmaf(xz[(size_t)(bl - 2) * (2 * EDx) + e], w.y, acc);
  if (l - 1 >= 0) acc = fmaf(xz[(size_t)(bl - 1) * (2 * EDx) + e], w.z, acc);
  acc = fmaf(xz[(size_t)bl * (2 * EDx) + e], w.w, acc);
  xb[idx] = acc / (1.f + __expf(-acc));
}

// ==================== chunked selective scan ====================
// Chains ch = b*ED + e (4096). NC=32 chunks of CT=32 steps.
// Thread = (chunk c, chain ch), holds all 16 states in registers.

#define CVT4(V) { V.x = -__expf(V.x) * 1.44269504f; V.y = -__expf(V.y) * 1.44269504f; \
                  V.z = -__expf(V.z) * 1.44269504f; V.w = -__expf(V.w) * 1.44269504f; }

// P *= dA ; Q = dA*Q + dx*B
#define ST4PQ(Av, Pv, Qv, Bv) { \
  float a0 = exp2f(dl * Av.x); Pv.x *= a0; Qv.x = fmaf(a0, Qv.x, dx * Bv.x); \
  float a1 = exp2f(dl * Av.y); Pv.y *= a1; Qv.y = fmaf(a1, Qv.y, dx * Bv.y); \
  float a2 = exp2f(dl * Av.z); Pv.z *= a2; Qv.z = fmaf(a2, Qv.z, dx * Bv.z); \
  float a3 = exp2f(dl * Av.w); Pv.w *= a3; Qv.w = fmaf(a3, Qv.w, dx * Bv.w); }

// h = dA*h + dx*B ; y += h*C
#define ST4Y(Av, Hv, Bv, Cv) { \
  float a0 = exp2f(dl * Av.x); Hv.x = fmaf(a0, Hv.x, dx * Bv.x); y = fmaf(Hv.x, Cv.x, y); \
  float a1 = exp2f(dl * Av.y); Hv.y = fmaf(a1, Hv.y, dx * Bv.y); y = fmaf(Hv.y, Cv.y, y); \
  float a2 = exp2f(dl * Av.z); Hv.z = fmaf(a2, Hv.z, dx * Bv.z); y = fmaf(Hv.z, Cv.z, y); \
  float a3 = exp2f(dl * Av.w); Hv.w = fmaf(a3, Hv.w, dx * Bv.w); y = fmaf(Hv.w, Cv.w, y); }

// Pass 1: per (chunk, chain) compute chunk transition (P = prod dA, Q = local scan from 0).
__global__ __launch_bounds__(256) void k_scan1(
    const float* __restrict__ del, const float* __restrict__ xb,
    const float* __restrict__ dbc, const float* __restrict__ Alog,
    float* __restrict__ PQ) {
  const int idx = blockIdx.x * 256 + threadIdx.x;   // c*4096 + ch
  const int ch = idx & 4095, c = idx >> 12;
  const int b = ch >> 10, e = ch & 1023;
  float4 A0, A1, A2, A3;
  {
    const float4* ar = (const float4*)(Alog + e * DS);
    A0 = ar[0]; A1 = ar[1]; A2 = ar[2]; A3 = ar[3];
    CVT4(A0); CVT4(A1); CVT4(A2); CVT4(A3);
  }
  float4 P0 = {1,1,1,1}, P1 = {1,1,1,1}, P2 = {1,1,1,1}, P3 = {1,1,1,1};
  float4 Q0 = {0,0,0,0}, Q1 = {0,0,0,0}, Q2 = {0,0,0,0}, Q3 = {0,0,0,0};
  const size_t bl0 = (size_t)b * Lx + c * CT;
  const float* dp  = del + bl0 * EDx + e;
  const float* xp  = xb  + bl0 * EDx + e;
  const float* bcp = dbc + bl0 * 64 + 32;
  #pragma unroll 2
  for (int i = 0; i < CT; ++i) {
    float dl = dp[0];
    float xbl = xp[0];
    float dx = dl * xbl;
    const float4* bp = (const float4*)bcp;
    float4 B0 = bp[0], B1 = bp[1], B2 = bp[2], B3 = bp[3];
    ST4PQ(A0, P0, Q0, B0); ST4PQ(A1, P1, Q1, B1);
    ST4PQ(A2, P2, Q2, B2); ST4PQ(A3, P3, Q3, B3);
    dp += EDx; xp += EDx; bcp += 64;
  }
  float4* o = (float4*)(PQ + (size_t)idx * 32);
  o[0] = P0; o[1] = P1; o[2] = P2; o[3] = P3;
  o[4] = Q0; o[5] = Q1; o[6] = Q2; o[7] = Q3;
}

// Pass 2: sequential combine over chunks; overwrite Q slot with carry-in h.
__global__ __launch_bounds__(256) void k_scan2(float* __restrict__ PQ) {
  const int idx = blockIdx.x * 256 + threadIdx.x;   // ch*16 + n
  const int ch = idx >> 4, n = idx & 15;
  float H = 0.f;
  for (int c = 0; c < NC; ++c) {
    size_t base = ((size_t)c * 4096 + ch) * 32;
    float Pv = PQ[base + n];
    float Qv = PQ[base + 16 + n];
    PQ[base + 16 + n] = H;          // h entering chunk c
    H = fmaf(Pv, H, Qv);
  }
}

// Pass 3: recompute chunk interior from carry-in; fuse y = (sum h*C + D*xb) * silu(z).
__global__ __launch_bounds__(256) void k_scan3(
    float* __restrict__ dy,               // in: delta, out: y (in place)
    const float* __restrict__ xb,
    const float* __restrict__ dbc,
    const float* __restrict__ xz,         // z at column offset ED
    const float* __restrict__ Alog, const float* __restrict__ Dp,
    const float* __restrict__ PQ) {
  const int idx = blockIdx.x * 256 + threadIdx.x;   // c*4096 + ch
  const int ch = idx & 4095, c = idx >> 12;
  const int b = ch >> 10, e = ch & 1023;
  float4 A0, A1, A2, A3;
  {
    const float4* ar = (const float4*)(Alog + e * DS);
    A0 = ar[0]; A1 = ar[1]; A2 = ar[2]; A3 = ar[3];
    CVT4(A0); CVT4(A1); CVT4(A2); CVT4(A3);
  }
  float4 H0, H1, H2, H3;
  {
    const float4* hi = (const float4*)(PQ + (size_t)idx * 32 + 16);
    H0 = hi[0]; H1 = hi[1]; H2 = hi[2]; H3 = hi[3];
  }
  const float De = Dp[e];
  const size_t bl0 = (size_t)b * Lx + c * CT;
  float* dyp = dy + bl0 * EDx + e;
  const float* xp  = xb + bl0 * EDx + e;
  const float* bcp = dbc + bl0 * 64 + 32;
  const float* zp  = xz + bl0 * (2 * EDx) + EDx + e;
  #pragma unroll 2
  for (int i = 0; i < CT; ++i) {
    float dl = dyp[0];
    float xbl = xp[0];
    float zv = zp[0];
    float dx = dl * xbl;
    const float4* bp = (const float4*)bcp;
    float4 B0 = bp[0], B1 = bp[1], B2 = bp[2], B3 = bp[3];
    float4 C0 = bp[4], C1 = bp[5], C2 = bp[6], C3 = bp[7];
    float y = 0.f;
    ST4Y(A0, H0, B0, C0); ST4Y(A1, H1, B1, C1);
    ST4Y(A2, H2, B2, C2); ST4Y(A3, H3, B3, C3);
    y = fmaf(De, xbl, y);
    y *= zv / (1.f + __expf(-zv));
    dyp[0] = y;
    dyp += EDx; xp += EDx; bcp += 64; zp += 2 * EDx;
  }
}

// ---------------- last-token LayerNorm + head ----------------
__global__ __launch_bounds__(256) void k_ln_head(
    const float* __restrict__ x, const float* __restrict__ g,
    const float* __restrict__ be, const float* __restrict__ Wo,
    const float* __restrict__ bo, float* __restrict__ out) {
  const int b = blockIdx.x;
  const int t = threadIdx.x;
  const float* xr = x + ((size_t)b * Lx + (Lx - 1)) * DM;
  __shared__ float w1[4], w2[4];
  __shared__ float xn[DM];
  __shared__ float hp[20][8];
  float a0 = xr[t], a1 = xr[t + 256];
  float p = a0 + a1;
  #pragma unroll
  for (int o = 32; o > 0; o >>= 1) p += __shfl_down(p, o);
  if ((t & 63) == 0) w1[t >> 6] = p;
  __syncthreads();
  float mean = (w1[0] + w1[1] + w1[2] + w1[3]) * (1.f / DM);
  float d0 = a0 - mean, d1 = a1 - mean;
  p = d0 * d0 + d1 * d1;
  #pragma unroll
  for (int o = 32; o > 0; o >>= 1) p += __shfl_down(p, o);
  if ((t & 63) == 0) w2[t >> 6] = p;
  __syncthreads();
  float rstd = rsqrtf((w2[0] + w2[1] + w2[2] + w2[3]) * (1.f / DM) + 1e-5f);
  xn[t] = d0 * rstd * g[t] + be[t];
  xn[t + 256] = d1 * rstd * g[t + 256] + be[t + 256];
  __syncthreads();
  if (t < 160) {
    int j = t / 8, sg = t % 8;
    const float* wr = Wo + (size_t)j * DM + sg * 64;
    const float* xs = xn + sg * 64;
    float s = 0.f;
    #pragma unroll
    for (int k = 0; k < 64; ++k) s = fmaf(xs[k], wr[k], s);
    hp[j][sg] = s;
  }
  __syncthreads();
  if (t < 20) {
    float s = bo[t];
    #pragma unroll
    for (int k = 0; k < 8; ++k) s += hp[t][k];
    out[b * 20 + t] = s;
  }
}

extern "C" void kernel_launch(void* const* d_in, const int* in_sizes, int n_in,
                              void* d_out, int out_size, void* d_ws, size_t ws_size,
                              hipStream_t stream) {
  (void)in_sizes; (void)n_in; (void)out_size; (void)ws_size;
  const float* seq    = (const float*)d_in[0];
  const float* Wi     = (const float*)d_in[1];
  const float* bi     = (const float*)d_in[2];
  const float* Wo     = (const float*)d_in[3];
  const float* bo     = (const float*)d_in[4];
  const float* ln_g   = (const float*)d_in[5];
  const float* ln_b   = (const float*)d_in[6];
  const float* lWin   = (const float*)d_in[7];
  const float* lconvw = (const float*)d_in[8];
  const float* lconvb = (const float*)d_in[9];
  const float* lWx    = (const float*)d_in[10];
  const float* lWdt   = (const float*)d_in[11];
  const float* lbdt   = (const float*)d_in[12];
  const float* lAlog  = (const float*)d_in[13];
  const float* lD     = (const float*)d_in[14];
  const float* lWout  = (const float*)d_in[15];

  float* ws  = (float*)d_ws;
  float* X   = ws;                 // [4096][512]   = 2M floats
  float* XZ  = X + 2097152;        // [4096][2048]  = 8M floats
  float* XB  = XZ + 8388608;       // [4096][1024]  = 4M floats
  float* DBC = XB + 4194304;       // [4096][64]    = 256K floats
  float* DEL = DBC + 262144;       // [4096][1024]  = 4M floats (delta, then y in-place)
  float* PQ  = DEL + 4194304;      // [NC*4096][32] = 4M floats

  k_init_x<<<dim3(Bx * Lx * DM / 256), 256, 0, stream>>>(seq, Wi, bi, X);

  for (int i = 0; i < NL; ++i) {
    const float* Win  = lWin   + (size_t)i * 2048 * 512;
    const float* cw   = lconvw + (size_t)i * EDx * 4;
    const float* cb   = lconvb + (size_t)i * EDx;
    const float* Wx   = lWx    + (size_t)i * 64 * EDx;
    const float* Wdt  = lWdt   + (size_t)i * EDx * DTR;
    const float* bdt  = lbdt   + (size_t)i * EDx;
    const float* Alog = lAlog  + (size_t)i * EDx * DS;
    const float* Dp   = lD     + (size_t)i * EDx;
    const float* Wout = lWout  + (size_t)i * DM * EDx;

    // xz = x @ Win^T            [4096,2048] K=512
    k_gemm_tn<128, 128, 0><<<dim3(32, 16), 256, 0, stream>>>(X, DM, Win, DM, nullptr, XZ, 2 * EDx, DM);
    // xb = silu(causal_dwconv(xz[:, :ED]) + cb)
    k_conv_silu<<<dim3(Bx * Lx * EDx / 256), 256, 0, stream>>>(XZ, cw, cb, XB);
    // dbc = xb @ Wx^T           [4096,64] K=1024
    k_gemm_tn<64, 16, 0><<<dim3(64, 4), 256, 0, stream>>>(XB, EDx, Wx, EDx, nullptr, DBC, 64, EDx);
    // delta = softplus(dbc[:, :32] @ Wdt^T + bdt)   [4096,1024] K=32
    k_gemm_tn<128, 64, 1><<<dim3(32, 16), 256, 0, stream>>>(DBC, 64, Wdt, DTR, bdt, DEL, EDx, DTR);
    // chunked selective scan + gating, y written over DEL
    k_scan1<<<dim3(4096 * NC / 256), 256, 0, stream>>>(DEL, XB, DBC, Alog, PQ);
    k_scan2<<<dim3(4096 * DS / 256), 256, 0, stream>>>(PQ);
    k_scan3<<<dim3(4096 * NC / 256), 256, 0, stream>>>(DEL, XB, DBC, XZ, Alog, Dp, PQ);
    // x = y @ Wout^T            [4096,512] K=1024
    k_gemm_tn<128, 64, 0><<<dim3(32, 8), 256, 0, stream>>>(DEL, EDx, Wout, EDx, nullptr, X, DM, EDx);
  }

  k_ln_head<<<dim3(Bx), 256, 0, stream>>>(X, ln_g, ln_b, Wo, bo, (float*)d_out);
}

// Round 5
// 1131.689 us; speedup vs baseline: 1.9711x; 1.4592x over previous
//
#include <hip/hip_runtime.h>
#include <hip/hip_bf16.h>
#include <math.h>

constexpr int Bx = 4, Lx = 1024, DM = 512, DS = 16, NL = 4, EDx = 1024;
constexpr int DTR = 32;
constexpr int NC = 32, CT = Lx / NC;   // 32 chunks x 32 steps

typedef __attribute__((ext_vector_type(8))) short short8v;   // 8 bf16 = 4 VGPR
typedef __attribute__((ext_vector_type(4))) float f32x4;

__device__ inline short f2bf(float f) {
  union { __hip_bfloat16 h; short s; } u;
  u.h = __float2bfloat16(f);
  return u.s;
}
__device__ inline float bf2f(short s) {
  union { __hip_bfloat16 h; short s; } u;
  u.s = s;
  return __bfloat162float(u.h);
}

// ---------------- x = seq @ Wi^T + bi ----------------
__global__ __launch_bounds__(256) void k_init_x(const float* __restrict__ seq,
    const float* __restrict__ Wi, const float* __restrict__ bi, float* __restrict__ x) {
  int idx = blockIdx.x * 256 + threadIdx.x;      // over B*L*DM
  int d = idx & (DM - 1);
  int bl = idx >> 9;
  float s0 = seq[bl * 3 + 0], s1 = seq[bl * 3 + 1], s2 = seq[bl * 3 + 2];
  x[idx] = bi[d] + s0 * Wi[d * 3 + 0] + s1 * Wi[d * 3 + 1] + s2 * Wi[d * 3 + 2];
}

// ============ split-fp32 (bf16x3) MFMA GEMM: C[M,N] = A[M,K] @ W[N,K]^T ============
// 4 waves in 2x2; wave tile (BM/2)x(BN/2); 16x16x32 bf16 MFMA, fp32 accum.
// a = ah + al (bf16 high/low); a*b ~= ah*bh + ah*bl + al*bh  (al*bl ~ 2^-18, dropped)
template <int BM, int BN>
__global__ __launch_bounds__(256) void k_gemm_mfma(
    const float* __restrict__ A, int lda,
    const float* __restrict__ W, int ldw,
    float* __restrict__ C, int ldc, int K) {
  constexpr int MR = BM / 32, NR = BN / 32;      // frags per wave
  __shared__ short Ah[BM][40], Al[BM][40], Bh[BN][40], Bl[BN][40];
  const int tid = threadIdx.x;
  const int w = tid >> 6, lane = tid & 63;
  const int wr = w >> 1, wc = w & 1;
  const int r16 = lane & 15, kh = lane >> 4;     // kh in 0..3
  const int m0 = blockIdx.x * BM, n0 = blockIdx.y * BN;

  f32x4 acc[MR][NR];
  #pragma unroll
  for (int i = 0; i < MR; ++i)
    #pragma unroll
    for (int j = 0; j < NR; ++j) {
      acc[i][j][0] = 0.f; acc[i][j][1] = 0.f; acc[i][j][2] = 0.f; acc[i][j][3] = 0.f;
    }

  for (int k0 = 0; k0 < K; k0 += 32) {
    __syncthreads();
    // stage A tile [BM][32] fp32 -> bf16 hi/lo
    #pragma unroll
    for (int p = 0; p < BM / 32; ++p) {
      int f = tid + p * 256;
      int r = f >> 3, c = (f & 7) << 2;
      const float4 v = *(const float4*)(A + (size_t)(m0 + r) * lda + k0 + c);
      short h0 = f2bf(v.x), h1 = f2bf(v.y), h2 = f2bf(v.z), h3 = f2bf(v.w);
      Ah[r][c + 0] = h0; Ah[r][c + 1] = h1; Ah[r][c + 2] = h2; Ah[r][c + 3] = h3;
      Al[r][c + 0] = f2bf(v.x - bf2f(h0));
      Al[r][c + 1] = f2bf(v.y - bf2f(h1));
      Al[r][c + 2] = f2bf(v.z - bf2f(h2));
      Al[r][c + 3] = f2bf(v.w - bf2f(h3));
    }
    // stage B tile [BN][32]
    #pragma unroll
    for (int p = 0; p < BN / 32; ++p) {
      int f = tid + p * 256;
      int r = f >> 3, c = (f & 7) << 2;
      const float4 v = *(const float4*)(W + (size_t)(n0 + r) * ldw + k0 + c);
      short h0 = f2bf(v.x), h1 = f2bf(v.y), h2 = f2bf(v.z), h3 = f2bf(v.w);
      Bh[r][c + 0] = h0; Bh[r][c + 1] = h1; Bh[r][c + 2] = h2; Bh[r][c + 3] = h3;
      Bl[r][c + 0] = f2bf(v.x - bf2f(h0));
      Bl[r][c + 1] = f2bf(v.y - bf2f(h1));
      Bl[r][c + 2] = f2bf(v.z - bf2f(h2));
      Bl[r][c + 3] = f2bf(v.w - bf2f(h3));
    }
    __syncthreads();
    // fragment loads: lane holds row (l&15), k = (l>>4)*8 .. +8 (8 consecutive bf16)
    short8v ah[MR], al[MR], bh[NR], bl[NR];
    #pragma unroll
    for (int i = 0; i < MR; ++i) {
      int rr = wr * (BM / 2) + i * 16 + r16;
      ah[i] = *(const short8v*)(&Ah[rr][kh * 8]);
      al[i] = *(const short8v*)(&Al[rr][kh * 8]);
    }
    #pragma unroll
    for (int j = 0; j < NR; ++j) {
      int cc = wc * (BN / 2) + j * 16 + r16;
      bh[j] = *(const short8v*)(&Bh[cc][kh * 8]);
      bl[j] = *(const short8v*)(&Bl[cc][kh * 8]);
    }
    #pragma unroll
    for (int i = 0; i < MR; ++i)
      #pragma unroll
      for (int j = 0; j < NR; ++j) {
        acc[i][j] = __builtin_amdgcn_mfma_f32_16x16x32_bf16(ah[i], bh[j], acc[i][j], 0, 0, 0);
        acc[i][j] = __builtin_amdgcn_mfma_f32_16x16x32_bf16(ah[i], bl[j], acc[i][j], 0, 0, 0);
        acc[i][j] = __builtin_amdgcn_mfma_f32_16x16x32_bf16(al[i], bh[j], acc[i][j], 0, 0, 0);
      }
  }
  // epilogue: D frag: col = lane&15, row = (lane>>4)*4 + reg   [m89-verified]
  #pragma unroll
  for (int i = 0; i < MR; ++i) {
    int row_base = m0 + wr * (BM / 2) + i * 16 + kh * 4;
    #pragma unroll
    for (int j = 0; j < NR; ++j) {
      int col = n0 + wc * (BN / 2) + j * 16 + r16;
      #pragma unroll
      for (int r = 0; r < 4; ++r)
        C[(size_t)(row_base + r) * ldc + col] = acc[i][j][r];
    }
  }
}

// ---------------- generic fp32 GEMM (kept for x_proj / dt_proj) ----------------
template <int BM, int BN, int EPI>
__global__ __launch_bounds__(256) void k_gemm_tn(
    const float* __restrict__ A, int lda,
    const float* __restrict__ W, int ldw,
    const float* __restrict__ bias,
    float* __restrict__ C, int ldc, int K) {
  constexpr int BK = 16;
  constexpr int MR = BM / 16, NR = BN / 16;
  __shared__ float As[BK][BM + 4];
  __shared__ float Bs[BK][BN + 4];
  const int tid = threadIdx.x;
  const int tx = tid & 15, ty = tid >> 4;
  const int m0 = blockIdx.x * BM, n0 = blockIdx.y * BN;
  const int arow = tid >> 2;           // 0..63
  const int akol = (tid & 3) << 2;     // 0,4,8,12
  float acc[MR][NR] = {};
  for (int k0 = 0; k0 < K; k0 += BK) {
    #pragma unroll
    for (int r = 0; r < BM / 64; ++r) {
      int m = arow + r * 64;
      const float4 v = *(const float4*)(A + (size_t)(m0 + m) * lda + k0 + akol);
      As[akol + 0][m] = v.x; As[akol + 1][m] = v.y;
      As[akol + 2][m] = v.z; As[akol + 3][m] = v.w;
    }
    if constexpr (BN >= 64) {
      #pragma unroll
      for (int r = 0; r < BN / 64; ++r) {
        int n = arow + r * 64;
        const float4 v = *(const float4*)(W + (size_t)(n0 + n) * ldw + k0 + akol);
        Bs[akol + 0][n] = v.x; Bs[akol + 1][n] = v.y;
        Bs[akol + 2][n] = v.z; Bs[akol + 3][n] = v.w;
      }
    } else {
      if (arow < BN) {
        const float4 v = *(const float4*)(W + (size_t)(n0 + arow) * ldw + k0 + akol);
        Bs[akol + 0][arow] = v.x; Bs[akol + 1][arow] = v.y;
        Bs[akol + 2][arow] = v.z; Bs[akol + 3][arow] = v.w;
      }
    }
    __syncthreads();
    #pragma unroll
    for (int k = 0; k < BK; ++k) {
      float af[MR], bf[NR];
      #pragma unroll
      for (int i = 0; i < MR; ++i) af[i] = As[k][ty * MR + i];
      #pragma unroll
      for (int j = 0; j < NR; ++j) bf[j] = Bs[k][tx * NR + j];
      #pragma unroll
      for (int i = 0; i < MR; ++i)
        #pragma unroll
        for (int j = 0; j < NR; ++j)
          acc[i][j] = fmaf(af[i], bf[j], acc[i][j]);
    }
    __syncthreads();
  }
  #pragma unroll
  for (int i = 0; i < MR; ++i) {
    int m = m0 + ty * MR + i;
    #pragma unroll
    for (int j = 0; j < NR; ++j) {
      int n = n0 + tx * NR + j;
      float v = acc[i][j];
      if constexpr (EPI == 1) {
        v += bias[n];
        v = (v > 20.f) ? v : log1pf(__expf(v));
      }
      C[(size_t)m * ldc + n] = v;
    }
  }
}

// ---------------- causal depthwise conv (D_CONV=4) + bias + silu ----------------
__global__ __launch_bounds__(256) void k_conv_silu(const float* __restrict__ xz,
    const float* __restrict__ cw, const float* __restrict__ cb, float* __restrict__ xb) {
  int idx = blockIdx.x * 256 + threadIdx.x;    // over B*L*ED
  int e = idx & (EDx - 1);
  int bl = idx >> 10;                          // b*L + l
  int l = bl & (Lx - 1);
  const float4 w = ((const float4*)cw)[e];
  float acc = cb[e];
  if (l - 3 >= 0) acc = fmaf(xz[(size_t)(bl - 3) * (2 * EDx) + e], w.x, acc);
  if (l - 2 >= 0) acc = fmaf(xz[(size_t)(bl - 2) * (2 * EDx) + e], w.y, acc);
  if (l - 1 >= 0) acc = fmaf(xz[(size_t)(bl - 1) * (2 * EDx) + e], w.z, acc);
  acc = fmaf(xz[(size_t)bl * (2 * EDx) + e], w.w, acc);
  xb[idx] = acc / (1.f + __expf(-acc));
}

// ==================== chunked selective scan ====================
#define CVT4(V) { V.x = -__expf(V.x) * 1.44269504f; V.y = -__expf(V.y) * 1.44269504f; \
                  V.z = -__expf(V.z) * 1.44269504f; V.w = -__expf(V.w) * 1.44269504f; }

#define ST4PQ(Av, Pv, Qv, Bv) { \
  float a0 = exp2f(dl * Av.x); Pv.x *= a0; Qv.x = fmaf(a0, Qv.x, dx * Bv.x); \
  float a1 = exp2f(dl * Av.y); Pv.y *= a1; Qv.y = fmaf(a1, Qv.y, dx * Bv.y); \
  float a2 = exp2f(dl * Av.z); Pv.z *= a2; Qv.z = fmaf(a2, Qv.z, dx * Bv.z); \
  float a3 = exp2f(dl * Av.w); Pv.w *= a3; Qv.w = fmaf(a3, Qv.w, dx * Bv.w); }

#define ST4Y(Av, Hv, Bv, Cv) { \
  float a0 = exp2f(dl * Av.x); Hv.x = fmaf(a0, Hv.x, dx * Bv.x); y = fmaf(Hv.x, Cv.x, y); \
  float a1 = exp2f(dl * Av.y); Hv.y = fmaf(a1, Hv.y, dx * Bv.y); y = fmaf(Hv.y, Cv.y, y); \
  float a2 = exp2f(dl * Av.z); Hv.z = fmaf(a2, Hv.z, dx * Bv.z); y = fmaf(Hv.z, Cv.z, y); \
  float a3 = exp2f(dl * Av.w); Hv.w = fmaf(a3, Hv.w, dx * Bv.w); y = fmaf(Hv.w, Cv.w, y); }

__global__ __launch_bounds__(256) void k_scan1(
    const float* __restrict__ del, const float* __restrict__ xb,
    const float* __restrict__ dbc, const float* __restrict__ Alog,
    float* __restrict__ PQ) {
  const int idx = blockIdx.x * 256 + threadIdx.x;   // c*4096 + ch
  const int ch = idx & 4095, c = idx >> 12;
  const int b = ch >> 10, e = ch & 1023;
  float4 A0, A1, A2, A3;
  {
    const float4* ar = (const float4*)(Alog + e * DS);
    A0 = ar[0]; A1 = ar[1]; A2 = ar[2]; A3 = ar[3];
    CVT4(A0); CVT4(A1); CVT4(A2); CVT4(A3);
  }
  float4 P0 = {1,1,1,1}, P1 = {1,1,1,1}, P2 = {1,1,1,1}, P3 = {1,1,1,1};
  float4 Q0 = {0,0,0,0}, Q1 = {0,0,0,0}, Q2 = {0,0,0,0}, Q3 = {0,0,0,0};
  const size_t bl0 = (size_t)b * Lx + c * CT;
  const float* dp  = del + bl0 * EDx + e;
  const float* xp  = xb  + bl0 * EDx + e;
  const float* bcp = dbc + bl0 * 64 + 32;
  #pragma unroll 2
  for (int i = 0; i < CT; ++i) {
    float dl = dp[0];
    float xbl = xp[0];
    float dx = dl * xbl;
    const float4* bp = (const float4*)bcp;
    float4 B0 = bp[0], B1 = bp[1], B2 = bp[2], B3 = bp[3];
    ST4PQ(A0, P0, Q0, B0); ST4PQ(A1, P1, Q1, B1);
    ST4PQ(A2, P2, Q2, B2); ST4PQ(A3, P3, Q3, B3);
    dp += EDx; xp += EDx; bcp += 64;
  }
  float4* o = (float4*)(PQ + (size_t)idx * 32);
  o[0] = P0; o[1] = P1; o[2] = P2; o[3] = P3;
  o[4] = Q0; o[5] = Q1; o[6] = Q2; o[7] = Q3;
}

__global__ __launch_bounds__(256) void k_scan2(float* __restrict__ PQ) {
  const int idx = blockIdx.x * 256 + threadIdx.x;   // ch*16 + n
  const int ch = idx >> 4, n = idx & 15;
  float H = 0.f;
  for (int c = 0; c < NC; ++c) {
    size_t base = ((size_t)c * 4096 + ch) * 32;
    float Pv = PQ[base + n];
    float Qv = PQ[base + 16 + n];
    PQ[base + 16 + n] = H;          // h entering chunk c
    H = fmaf(Pv, H, Qv);
  }
}

__global__ __launch_bounds__(256) void k_scan3(
    float* __restrict__ dy,               // in: delta, out: y (in place)
    const float* __restrict__ xb,
    const float* __restrict__ dbc,
    const float* __restrict__ xz,         // z at column offset ED
    const float* __restrict__ Alog, const float* __restrict__ Dp,
    const float* __restrict__ PQ) {
  const int idx = blockIdx.x * 256 + threadIdx.x;   // c*4096 + ch
  const int ch = idx & 4095, c = idx >> 12;
  const int b = ch >> 10, e = ch & 1023;
  float4 A0, A1, A2, A3;
  {
    const float4* ar = (const float4*)(Alog + e * DS);
    A0 = ar[0]; A1 = ar[1]; A2 = ar[2]; A3 = ar[3];
    CVT4(A0); CVT4(A1); CVT4(A2); CVT4(A3);
  }
  float4 H0, H1, H2, H3;
  {
    const float4* hi = (const float4*)(PQ + (size_t)idx * 32 + 16);
    H0 = hi[0]; H1 = hi[1]; H2 = hi[2]; H3 = hi[3];
  }
  const float De = Dp[e];
  const size_t bl0 = (size_t)b * Lx + c * CT;
  float* dyp = dy + bl0 * EDx + e;
  const float* xp  = xb + bl0 * EDx + e;
  const float* bcp = dbc + bl0 * 64 + 32;
  const float* zp  = xz + bl0 * (2 * EDx) + EDx + e;
  #pragma unroll 2
  for (int i = 0; i < CT; ++i) {
    float dl = dyp[0];
    float xbl = xp[0];
    float zv = zp[0];
    float dx = dl * xbl;
    const float4* bp = (const float4*)bcp;
    float4 B0 = bp[0], B1 = bp[1], B2 = bp[2], B3 = bp[3];
    float4 C0 = bp[4], C1 = bp[5], C2 = bp[6], C3 = bp[7];
    float y = 0.f;
    ST4Y(A0, H0, B0, C0); ST4Y(A1, H1, B1, C1);
    ST4Y(A2, H2, B2, C2); ST4Y(A3, H3, B3, C3);
    y = fmaf(De, xbl, y);
    y *= zv / (1.f + __expf(-zv));
    dyp[0] = y;
    dyp += EDx; xp += EDx; bcp += 64; zp += 2 * EDx;
  }
}

// ---------------- last-token LayerNorm + head ----------------
__global__ __launch_bounds__(256) void k_ln_head(
    const float* __restrict__ x, const float* __restrict__ g,
    const float* __restrict__ be, const float* __restrict__ Wo,
    const float* __restrict__ bo, float* __restrict__ out) {
  const int b = blockIdx.x;
  const int t = threadIdx.x;
  const float* xr = x + ((size_t)b * Lx + (Lx - 1)) * DM;
  __shared__ float w1[4], w2[4];
  __shared__ float xn[DM];
  __shared__ float hp[20][8];
  float a0 = xr[t], a1 = xr[t + 256];
  float p = a0 + a1;
  #pragma unroll
  for (int o = 32; o > 0; o >>= 1) p += __shfl_down(p, o);
  if ((t & 63) == 0) w1[t >> 6] = p;
  __syncthreads();
  float mean = (w1[0] + w1[1] + w1[2] + w1[3]) * (1.f / DM);
  float d0 = a0 - mean, d1 = a1 - mean;
  p = d0 * d0 + d1 * d1;
  #pragma unroll
  for (int o = 32; o > 0; o >>= 1) p += __shfl_down(p, o);
  if ((t & 63) == 0) w2[t >> 6] = p;
  __syncthreads();
  float rstd = rsqrtf((w2[0] + w2[1] + w2[2] + w2[3]) * (1.f / DM) + 1e-5f);
  xn[t] = d0 * rstd * g[t] + be[t];
  xn[t + 256] = d1 * rstd * g[t + 256] + be[t + 256];
  __syncthreads();
  if (t < 160) {
    int j = t / 8, sg = t % 8;
    const float* wr = Wo + (size_t)j * DM + sg * 64;
    const float* xs = xn + sg * 64;
    float s = 0.f;
    #pragma unroll
    for (int k = 0; k < 64; ++k) s = fmaf(xs[k], wr[k], s);
    hp[j][sg] = s;
  }
  __syncthreads();
  if (t < 20) {
    float s = bo[t];
    #pragma unroll
    for (int k = 0; k < 8; ++k) s += hp[t][k];
    out[b * 20 + t] = s;
  }
}

extern "C" void kernel_launch(void* const* d_in, const int* in_sizes, int n_in,
                              void* d_out, int out_size, void* d_ws, size_t ws_size,
                              hipStream_t stream) {
  (void)in_sizes; (void)n_in; (void)out_size; (void)ws_size;
  const float* seq    = (const float*)d_in[0];
  const float* Wi     = (const float*)d_in[1];
  const float* bi     = (const float*)d_in[2];
  const float* Wo     = (const float*)d_in[3];
  const float* bo     = (const float*)d_in[4];
  const float* ln_g   = (const float*)d_in[5];
  const float* ln_b   = (const float*)d_in[6];
  const float* lWin   = (const float*)d_in[7];
  const float* lconvw = (const float*)d_in[8];
  const float* lconvb = (const float*)d_in[9];
  const float* lWx    = (const float*)d_in[10];
  const float* lWdt   = (const float*)d_in[11];
  const float* lbdt   = (const float*)d_in[12];
  const float* lAlog  = (const float*)d_in[13];
  const float* lD     = (const float*)d_in[14];
  const float* lWout  = (const float*)d_in[15];

  float* ws  = (float*)d_ws;
  float* X   = ws;                 // [4096][512]   = 2M floats
  float* XZ  = X + 2097152;        // [4096][2048]  = 8M floats
  float* XB  = XZ + 8388608;       // [4096][1024]  = 4M floats
  float* DBC = XB + 4194304;       // [4096][64]    = 256K floats
  float* DEL = DBC + 262144;       // [4096][1024]  = 4M floats (delta, then y in-place)
  float* PQ  = DEL + 4194304;      // [NC*4096][32] = 4M floats

  k_init_x<<<dim3(Bx * Lx * DM / 256), 256, 0, stream>>>(seq, Wi, bi, X);

  for (int i = 0; i < NL; ++i) {
    const float* Win  = lWin   + (size_t)i * 2048 * 512;
    const float* cw   = lconvw + (size_t)i * EDx * 4;
    const float* cb   = lconvb + (size_t)i * EDx;
    const float* Wx   = lWx    + (size_t)i * 64 * EDx;
    const float* Wdt  = lWdt   + (size_t)i * EDx * DTR;
    const float* bdt  = lbdt   + (size_t)i * EDx;
    const float* Alog = lAlog  + (size_t)i * EDx * DS;
    const float* Dp   = lD     + (size_t)i * EDx;
    const float* Wout = lWout  + (size_t)i * DM * EDx;

    // xz = x @ Win^T            [4096,2048] K=512   (bf16x3 MFMA)
    k_gemm_mfma<128, 128><<<dim3(32, 16), 256, 0, stream>>>(X, DM, Win, DM, XZ, 2 * EDx, DM);
    // xb = silu(causal_dwconv(xz[:, :ED]) + cb)
    k_conv_silu<<<dim3(Bx * Lx * EDx / 256), 256, 0, stream>>>(XZ, cw, cb, XB);
    // dbc = xb @ Wx^T           [4096,64] K=1024
    k_gemm_tn<64, 16, 0><<<dim3(64, 4), 256, 0, stream>>>(XB, EDx, Wx, EDx, nullptr, DBC, 64, EDx);
    // delta = softplus(dbc[:, :32] @ Wdt^T + bdt)   [4096,1024] K=32
    k_gemm_tn<128, 64, 1><<<dim3(32, 16), 256, 0, stream>>>(DBC, 64, Wdt, DTR, bdt, DEL, EDx, DTR);
    // chunked selective scan + gating, y written over DEL
    k_scan1<<<dim3(4096 * NC / 256), 256, 0, stream>>>(DEL, XB, DBC, Alog, PQ);
    k_scan2<<<dim3(4096 * DS / 256), 256, 0, stream>>>(PQ);
    k_scan3<<<dim3(4096 * NC / 256), 256, 0, stream>>>(DEL, XB, DBC, XZ, Alog, Dp, PQ);
    // x = y @ Wout^T            [4096,512] K=1024   (bf16x3 MFMA)
    k_gemm_mfma<128, 64><<<dim3(32, 8), 256, 0, stream>>>(DEL, EDx, Wout, EDx, X, DM, EDx);
  }

  k_ln_head<<<dim3(Bx), 256, 0, stream>>>(X, ln_g, ln_b, Wo, bo, (float*)d_out);
}

// Round 7
// 910.980 us; speedup vs baseline: 2.4487x; 1.2423x over previous
//
#include <hip/hip_runtime.h>
#include <hip/hip_bf16.h>
#include <math.h>

constexpr int Bx = 4, Lx = 1024, DM = 512, DS = 16, NL = 4, EDx = 1024;
constexpr int DTR = 32;

typedef __attribute__((ext_vector_type(8))) short short8v;   // 8 bf16 = 4 VGPR
typedef __attribute__((ext_vector_type(4))) float f32x4;

__device__ inline short f2bf(float f) {
  union { __hip_bfloat16 h; short s; } u;
  u.h = __float2bfloat16(f);
  return u.s;
}
__device__ inline float bf2f(short s) {
  union { __hip_bfloat16 h; short s; } u;
  u.s = s;
  return __bfloat162float(u.h);
}

// ---------------- x = seq @ Wi^T + bi ----------------
__global__ __launch_bounds__(256) void k_init_x(const float* __restrict__ seq,
    const float* __restrict__ Wi, const float* __restrict__ bi, float* __restrict__ x) {
  int idx = blockIdx.x * 256 + threadIdx.x;      // over B*L*DM
  int d = idx & (DM - 1);
  int bl = idx >> 9;
  float s0 = seq[bl * 3 + 0], s1 = seq[bl * 3 + 1], s2 = seq[bl * 3 + 2];
  x[idx] = bi[d] + s0 * Wi[d * 3 + 0] + s1 * Wi[d * 3 + 1] + s2 * Wi[d * 3 + 2];
}

// ============ split-fp32 (bf16x3) MFMA GEMM: C[M,N] = A[M,K] @ W[N,K]^T ============
// 4 waves 2x2; wave tile (BM/2)x(BN/2); 16x16x32 bf16 MFMA, fp32 accum.
// a = ah + al; a*b ~= ah*bh + ah*bl + al*bh   (al*bl ~2^-18 dropped)
template <int BM, int BN>
__global__ __launch_bounds__(256) void k_gemm_mfma(
    const float* __restrict__ A, int lda,
    const float* __restrict__ W, int ldw,
    float* __restrict__ C, int ldc, int K) {
  constexpr int MR = BM / 32, NR = BN / 32;
  __shared__ short Ah[BM][44], Al[BM][44], Bh[BN][44], Bl[BN][44];
  const int tid = threadIdx.x;
  const int w = tid >> 6, lane = tid & 63;
  const int wr = w >> 1, wc = w & 1;
  const int r16 = lane & 15, kh = lane >> 4;
  const int m0 = blockIdx.x * BM, n0 = blockIdx.y * BN;

  f32x4 acc[MR][NR];
  #pragma unroll
  for (int i = 0; i < MR; ++i)
    #pragma unroll
    for (int j = 0; j < NR; ++j) {
      acc[i][j][0] = 0.f; acc[i][j][1] = 0.f; acc[i][j][2] = 0.f; acc[i][j][3] = 0.f;
    }

  for (int k0 = 0; k0 < K; k0 += 32) {
    __syncthreads();
    #pragma unroll
    for (int p = 0; p < BM / 32; ++p) {
      int f = tid + p * 256;
      int r = f >> 3, c = (f & 7) << 2;
      const float4 v = *(const float4*)(A + (size_t)(m0 + r) * lda + k0 + c);
      short h0 = f2bf(v.x), h1 = f2bf(v.y), h2 = f2bf(v.z), h3 = f2bf(v.w);
      Ah[r][c + 0] = h0; Ah[r][c + 1] = h1; Ah[r][c + 2] = h2; Ah[r][c + 3] = h3;
      Al[r][c + 0] = f2bf(v.x - bf2f(h0));
      Al[r][c + 1] = f2bf(v.y - bf2f(h1));
      Al[r][c + 2] = f2bf(v.z - bf2f(h2));
      Al[r][c + 3] = f2bf(v.w - bf2f(h3));
    }
    #pragma unroll
    for (int p = 0; p < BN / 32; ++p) {
      int f = tid + p * 256;
      int r = f >> 3, c = (f & 7) << 2;
      const float4 v = *(const float4*)(W + (size_t)(n0 + r) * ldw + k0 + c);
      short h0 = f2bf(v.x), h1 = f2bf(v.y), h2 = f2bf(v.z), h3 = f2bf(v.w);
      Bh[r][c + 0] = h0; Bh[r][c + 1] = h1; Bh[r][c + 2] = h2; Bh[r][c + 3] = h3;
      Bl[r][c + 0] = f2bf(v.x - bf2f(h0));
      Bl[r][c + 1] = f2bf(v.y - bf2f(h1));
      Bl[r][c + 2] = f2bf(v.z - bf2f(h2));
      Bl[r][c + 3] = f2bf(v.w - bf2f(h3));
    }
    __syncthreads();
    short8v ah[MR], al[MR], bh[NR], bl[NR];
    #pragma unroll
    for (int i = 0; i < MR; ++i) {
      int rr = wr * (BM / 2) + i * 16 + r16;
      ah[i] = *(const short8v*)(&Ah[rr][kh * 8]);
      al[i] = *(const short8v*)(&Al[rr][kh * 8]);
    }
    #pragma unroll
    for (int j = 0; j < NR; ++j) {
      int cc = wc * (BN / 2) + j * 16 + r16;
      bh[j] = *(const short8v*)(&Bh[cc][kh * 8]);
      bl[j] = *(const short8v*)(&Bl[cc][kh * 8]);
    }
    #pragma unroll
    for (int i = 0; i < MR; ++i)
      #pragma unroll
      for (int j = 0; j < NR; ++j) {
        acc[i][j] = __builtin_amdgcn_mfma_f32_16x16x32_bf16(ah[i], bh[j], acc[i][j], 0, 0, 0);
        acc[i][j] = __builtin_amdgcn_mfma_f32_16x16x32_bf16(ah[i], bl[j], acc[i][j], 0, 0, 0);
        acc[i][j] = __builtin_amdgcn_mfma_f32_16x16x32_bf16(al[i], bh[j], acc[i][j], 0, 0, 0);
      }
  }
  #pragma unroll
  for (int i = 0; i < MR; ++i) {
    int row_base = m0 + wr * (BM / 2) + i * 16 + kh * 4;
    #pragma unroll
    for (int j = 0; j < NR; ++j) {
      int col = n0 + wc * (BN / 2) + j * 16 + r16;
      #pragma unroll
      for (int r = 0; r < 4; ++r)
        C[(size_t)(row_base + r) * ldc + col] = acc[i][j][r];
    }
  }
}

// ============ x_proj split-K bf16x3 MFMA: PART[sk] = XB @ Wx^T (K-slice) ============
template <int SK>
__global__ __launch_bounds__(256) void k_xproj_mfma(
    const float* __restrict__ A,      // XB [4096][1024]
    const float* __restrict__ W,      // Wx [64][1024]
    float* __restrict__ PART) {       // [SK][4096][64]
  constexpr int BM = 128, BN = 64, KS = 1024 / SK;
  constexpr int MR = 4, NR = 2;       // wave tile 64x32
  __shared__ short Ah[BM][44], Al[BM][44], Bh[BN][44], Bl[BN][44];
  const int tid = threadIdx.x;
  const int w = tid >> 6, lane = tid & 63;
  const int wr = w >> 1, wc = w & 1;
  const int r16 = lane & 15, kh = lane >> 4;
  const int m0 = blockIdx.x * BM;
  const int kbeg = blockIdx.z * KS;

  f32x4 acc[MR][NR];
  #pragma unroll
  for (int i = 0; i < MR; ++i)
    #pragma unroll
    for (int j = 0; j < NR; ++j) {
      acc[i][j][0] = 0.f; acc[i][j][1] = 0.f; acc[i][j][2] = 0.f; acc[i][j][3] = 0.f;
    }

  for (int k0 = kbeg; k0 < kbeg + KS; k0 += 32) {
    __syncthreads();
    #pragma unroll
    for (int p = 0; p < BM / 32; ++p) {
      int f = tid + p * 256;
      int r = f >> 3, c = (f & 7) << 2;
      const float4 v = *(const float4*)(A + (size_t)(m0 + r) * 1024 + k0 + c);
      short h0 = f2bf(v.x), h1 = f2bf(v.y), h2 = f2bf(v.z), h3 = f2bf(v.w);
      Ah[r][c + 0] = h0; Ah[r][c + 1] = h1; Ah[r][c + 2] = h2; Ah[r][c + 3] = h3;
      Al[r][c + 0] = f2bf(v.x - bf2f(h0));
      Al[r][c + 1] = f2bf(v.y - bf2f(h1));
      Al[r][c + 2] = f2bf(v.z - bf2f(h2));
      Al[r][c + 3] = f2bf(v.w - bf2f(h3));
    }
    #pragma unroll
    for (int p = 0; p < BN / 32; ++p) {
      int f = tid + p * 256;
      int r = f >> 3, c = (f & 7) << 2;
      const float4 v = *(const float4*)(W + (size_t)r * 1024 + k0 + c);
      short h0 = f2bf(v.x), h1 = f2bf(v.y), h2 = f2bf(v.z), h3 = f2bf(v.w);
      Bh[r][c + 0] = h0; Bh[r][c + 1] = h1; Bh[r][c + 2] = h2; Bh[r][c + 3] = h3;
      Bl[r][c + 0] = f2bf(v.x - bf2f(h0));
      Bl[r][c + 1] = f2bf(v.y - bf2f(h1));
      Bl[r][c + 2] = f2bf(v.z - bf2f(h2));
      Bl[r][c + 3] = f2bf(v.w - bf2f(h3));
    }
    __syncthreads();
    short8v ah[MR], al[MR], bh[NR], bl[NR];
    #pragma unroll
    for (int i = 0; i < MR; ++i) {
      int rr = wr * 64 + i * 16 + r16;
      ah[i] = *(const short8v*)(&Ah[rr][kh * 8]);
      al[i] = *(const short8v*)(&Al[rr][kh * 8]);
    }
    #pragma unroll
    for (int j = 0; j < NR; ++j) {
      int cc = wc * 32 + j * 16 + r16;
      bh[j] = *(const short8v*)(&Bh[cc][kh * 8]);
      bl[j] = *(const short8v*)(&Bl[cc][kh * 8]);
    }
    #pragma unroll
    for (int i = 0; i < MR; ++i)
      #pragma unroll
      for (int j = 0; j < NR; ++j) {
        acc[i][j] = __builtin_amdgcn_mfma_f32_16x16x32_bf16(ah[i], bh[j], acc[i][j], 0, 0, 0);
        acc[i][j] = __builtin_amdgcn_mfma_f32_16x16x32_bf16(ah[i], bl[j], acc[i][j], 0, 0, 0);
        acc[i][j] = __builtin_amdgcn_mfma_f32_16x16x32_bf16(al[i], bh[j], acc[i][j], 0, 0, 0);
      }
  }
  float* Cp = PART + (size_t)blockIdx.z * (4096 * 64);
  #pragma unroll
  for (int i = 0; i < MR; ++i) {
    int row_base = m0 + wr * 64 + i * 16 + kh * 4;
    #pragma unroll
    for (int j = 0; j < NR; ++j) {
      int col = wc * 32 + j * 16 + r16;
      #pragma unroll
      for (int r = 0; r < 4; ++r)
        Cp[(size_t)(row_base + r) * 64 + col] = acc[i][j][r];
    }
  }
}

template <int SK>
__global__ __launch_bounds__(256) void k_redux(const float* __restrict__ PART,
                                               float* __restrict__ out) {
  int i = blockIdx.x * 256 + threadIdx.x;      // over 4096*64/4 float4s
  float4 s = ((const float4*)PART)[i];
  #pragma unroll
  for (int k = 1; k < SK; ++k) {
    const float4 v = ((const float4*)PART)[i + k * 65536];
    s.x += v.x; s.y += v.y; s.z += v.z; s.w += v.w;
  }
  ((float4*)out)[i] = s;
}

// ---------------- generic fp32 GEMM (kept for dt_proj) ----------------
template <int BM, int BN, int EPI>
__global__ __launch_bounds__(256) void k_gemm_tn(
    const float* __restrict__ A, int lda,
    const float* __restrict__ W, int ldw,
    const float* __restrict__ bias,
    float* __restrict__ C, int ldc, int K) {
  constexpr int BK = 16;
  constexpr int MR = BM / 16, NR = BN / 16;
  __shared__ float As[BK][BM + 4];
  __shared__ float Bs[BK][BN + 4];
  const int tid = threadIdx.x;
  const int tx = tid & 15, ty = tid >> 4;
  const int m0 = blockIdx.x * BM, n0 = blockIdx.y * BN;
  const int arow = tid >> 2;
  const int akol = (tid & 3) << 2;
  float acc[MR][NR] = {};
  for (int k0 = 0; k0 < K; k0 += BK) {
    #pragma unroll
    for (int r = 0; r < BM / 64; ++r) {
      int m = arow + r * 64;
      const float4 v = *(const float4*)(A + (size_t)(m0 + m) * lda + k0 + akol);
      As[akol + 0][m] = v.x; As[akol + 1][m] = v.y;
      As[akol + 2][m] = v.z; As[akol + 3][m] = v.w;
    }
    if constexpr (BN >= 64) {
      #pragma unroll
      for (int r = 0; r < BN / 64; ++r) {
        int n = arow + r * 64;
        const float4 v = *(const float4*)(W + (size_t)(n0 + n) * ldw + k0 + akol);
        Bs[akol + 0][n] = v.x; Bs[akol + 1][n] = v.y;
        Bs[akol + 2][n] = v.z; Bs[akol + 3][n] = v.w;
      }
    } else {
      if (arow < BN) {
        const float4 v = *(const float4*)(W + (size_t)(n0 + arow) * ldw + k0 + akol);
        Bs[akol + 0][arow] = v.x; Bs[akol + 1][arow] = v.y;
        Bs[akol + 2][arow] = v.z; Bs[akol + 3][arow] = v.w;
      }
    }
    __syncthreads();
    #pragma unroll
    for (int k = 0; k < BK; ++k) {
      float af[MR], bf[NR];
      #pragma unroll
      for (int i = 0; i < MR; ++i) af[i] = As[k][ty * MR + i];
      #pragma unroll
      for (int j = 0; j < NR; ++j) bf[j] = Bs[k][tx * NR + j];
      #pragma unroll
      for (int i = 0; i < MR; ++i)
        #pragma unroll
        for (int j = 0; j < NR; ++j)
          acc[i][j] = fmaf(af[i], bf[j], acc[i][j]);
    }
    __syncthreads();
  }
  #pragma unroll
  for (int i = 0; i < MR; ++i) {
    int m = m0 + ty * MR + i;
    #pragma unroll
    for (int j = 0; j < NR; ++j) {
      int n = n0 + tx * NR + j;
      float v = acc[i][j];
      if constexpr (EPI == 1) {
        v += bias[n];
        v = (v > 20.f) ? v : log1pf(__expf(v));
      }
      C[(size_t)m * ldc + n] = v;
    }
  }
}

// ---------------- causal depthwise conv (D_CONV=4) + bias + silu ----------------
__global__ __launch_bounds__(256) void k_conv_silu(const float* __restrict__ xz,
    const float* __restrict__ cw, const float* __restrict__ cb, float* __restrict__ xb) {
  int idx = blockIdx.x * 256 + threadIdx.x;    // over B*L*ED
  int e = idx & (EDx - 1);
  int bl = idx >> 10;                          // b*L + l
  int l = bl & (Lx - 1);
  const float4 w = ((const float4*)cw)[e];
  float acc = cb[e];
  if (l - 3 >= 0) acc = fmaf(xz[(size_t)(bl - 3) * (2 * EDx) + e], w.x, acc);
  if (l - 2 >= 0) acc = fmaf(xz[(size_t)(bl - 2) * (2 * EDx) + e], w.y, acc);
  if (l - 1 >= 0) acc = fmaf(xz[(size_t)(bl - 1) * (2 * EDx) + e], w.z, acc);
  acc = fmaf(xz[(size_t)bl * (2 * EDx) + e], w.w, acc);
  xb[idx] = acc / (1.f + __expf(-acc));
}

// ==================== chunked selective scan (templated on chunk count) ====================
#define CVT4(V) { V.x = -__expf(V.x) * 1.44269504f; V.y = -__expf(V.y) * 1.44269504f; \
                  V.z = -__expf(V.z) * 1.44269504f; V.w = -__expf(V.w) * 1.44269504f; }

#define ST4PQ(Av, Pv, Qv, Bv) { \
  float a0 = exp2f(dl * Av.x); Pv.x *= a0; Qv.x = fmaf(a0, Qv.x, dx * Bv.x); \
  float a1 = exp2f(dl * Av.y); Pv.y *= a1; Qv.y = fmaf(a1, Qv.y, dx * Bv.y); \
  float a2 = exp2f(dl * Av.z); Pv.z *= a2; Qv.z = fmaf(a2, Qv.z, dx * Bv.z); \
  float a3 = exp2f(dl * Av.w); Pv.w *= a3; Qv.w = fmaf(a3, Qv.w, dx * Bv.w); }

#define ST4Y(Av, Hv, Bv, Cv) { \
  float a0 = exp2f(dl * Av.x); Hv.x = fmaf(a0, Hv.x, dx * Bv.x); y = fmaf(Hv.x, Cv.x, y); \
  float a1 = exp2f(dl * Av.y); Hv.y = fmaf(a1, Hv.y, dx * Bv.y); y = fmaf(Hv.y, Cv.y, y); \
  float a2 = exp2f(dl * Av.z); Hv.z = fmaf(a2, Hv.z, dx * Bv.z); y = fmaf(Hv.z, Cv.z, y); \
  float a3 = exp2f(dl * Av.w); Hv.w = fmaf(a3, Hv.w, dx * Bv.w); y = fmaf(Hv.w, Cv.w, y); }

template <int NCt>
__global__ __launch_bounds__(256) void k_scan1(
    const float* __restrict__ del, const float* __restrict__ xb,
    const float* __restrict__ dbc, const float* __restrict__ Alog,
    float* __restrict__ PQ) {
  constexpr int CTt = Lx / NCt;
  const int idx = blockIdx.x * 256 + threadIdx.x;   // c*4096 + ch
  const int ch = idx & 4095, c = idx >> 12;
  const int b = ch >> 10, e = ch & 1023;
  float4 A0, A1, A2, A3;
  {
    const float4* ar = (const float4*)(Alog + e * DS);
    A0 = ar[0]; A1 = ar[1]; A2 = ar[2]; A3 = ar[3];
    CVT4(A0); CVT4(A1); CVT4(A2); CVT4(A3);
  }
  float4 P0 = {1,1,1,1}, P1 = {1,1,1,1}, P2 = {1,1,1,1}, P3 = {1,1,1,1};
  float4 Q0 = {0,0,0,0}, Q1 = {0,0,0,0}, Q2 = {0,0,0,0}, Q3 = {0,0,0,0};
  const size_t bl0 = (size_t)b * Lx + c * CTt;
  const float* dp  = del + bl0 * EDx + e;
  const float* xp  = xb  + bl0 * EDx + e;
  const float* bcp = dbc + bl0 * 64 + 32;
  #pragma unroll 2
  for (int i = 0; i < CTt; ++i) {
    float dl = dp[0];
    float xbl = xp[0];
    float dx = dl * xbl;
    const float4* bp = (const float4*)bcp;
    float4 B0 = bp[0], B1 = bp[1], B2 = bp[2], B3 = bp[3];
    ST4PQ(A0, P0, Q0, B0); ST4PQ(A1, P1, Q1, B1);
    ST4PQ(A2, P2, Q2, B2); ST4PQ(A3, P3, Q3, B3);
    dp += EDx; xp += EDx; bcp += 64;
  }
  float4* o = (float4*)(PQ + (size_t)idx * 32);
  o[0] = P0; o[1] = P1; o[2] = P2; o[3] = P3;
  o[4] = Q0; o[5] = Q1; o[6] = Q2; o[7] = Q3;
}

// Pass 2: sequential combine over chunks, 8-deep two-bank software pipeline.
template <int NCt>
__global__ __launch_bounds__(256) void k_scan2(float* __restrict__ PQ) {
  const int idx = blockIdx.x * 256 + threadIdx.x;   // ch*16 + n
  const int ch = idx >> 4, n = idx & 15;
  constexpr int G = 8;
  const size_t off = (size_t)ch * 32 + n;
  float Pa[G], Qa[G], Pb[G], Qb[G];
  #pragma unroll
  for (int j = 0; j < G; ++j) {
    size_t base = (size_t)j * (4096 * 32) + off;
    Pa[j] = PQ[base]; Qa[j] = PQ[base + 16];
  }
  float H = 0.f;
  #pragma unroll
  for (int gp = 0; gp < NCt / (2 * G); ++gp) {
    const int cA = 2 * gp * G, cB = (2 * gp + 1) * G, cN = (2 * gp + 2) * G;
    #pragma unroll
    for (int j = 0; j < G; ++j) {
      size_t base = (size_t)(cB + j) * (4096 * 32) + off;
      Pb[j] = PQ[base]; Qb[j] = PQ[base + 16];
    }
    #pragma unroll
    for (int j = 0; j < G; ++j) {
      size_t base = (size_t)(cA + j) * (4096 * 32) + off;
      PQ[base + 16] = H;                  // carry-in for chunk cA+j
      H = fmaf(Pa[j], H, Qa[j]);
    }
    if (gp + 1 < NCt / (2 * G)) {
      #pragma unroll
      for (int j = 0; j < G; ++j) {
        size_t base = (size_t)(cN + j) * (4096 * 32) + off;
        Pa[j] = PQ[base]; Qa[j] = PQ[base + 16];
      }
    }
    #pragma unroll
    for (int j = 0; j < G; ++j) {
      size_t base = (size_t)(cB + j) * (4096 * 32) + off;
      PQ[base + 16] = H;
      H = fmaf(Pb[j], H, Qb[j]);
    }
  }
}

template <int NCt>
__global__ __launch_bounds__(256) void k_scan3(
    float* __restrict__ dy,               // in: delta, out: y (in place)
    const float* __restrict__ xb,
    const float* __restrict__ dbc,
    const float* __restrict__ xz,         // z at column offset ED
    const float* __restrict__ Alog, const float* __restrict__ Dp,
    const float* __restrict__ PQ) {
  constexpr int CTt = Lx / NCt;
  const int idx = blockIdx.x * 256 + threadIdx.x;   // c*4096 + ch
  const int ch = idx & 4095, c = idx >> 12;
  const int b = ch >> 10, e = ch & 1023;
  float4 A0, A1, A2, A3;
  {
    const float4* ar = (const float4*)(Alog + e * DS);
    A0 = ar[0]; A1 = ar[1]; A2 = ar[2]; A3 = ar[3];
    CVT4(A0); CVT4(A1); CVT4(A2); CVT4(A3);
  }
  float4 H0, H1, H2, H3;
  {
    const float4* hi = (const float4*)(PQ + (size_t)idx * 32 + 16);
    H0 = hi[0]; H1 = hi[1]; H2 = hi[2]; H3 = hi[3];
  }
  const float De = Dp[e];
  const size_t bl0 = (size_t)b * Lx + c * CTt;
  float* dyp = dy + bl0 * EDx + e;
  const float* xp  = xb + bl0 * EDx + e;
  const float* bcp = dbc + bl0 * 64 + 32;
  const float* zp  = xz + bl0 * (2 * EDx) + EDx + e;
  #pragma unroll 2
  for (int i = 0; i < CTt; ++i) {
    float dl = dyp[0];
    float xbl = xp[0];
    float zv = zp[0];
    float dx = dl * xbl;
    const float4* bp = (const float4*)bcp;
    float4 B0 = bp[0], B1 = bp[1], B2 = bp[2], B3 = bp[3];
    float4 C0 = bp[4], C1 = bp[5], C2 = bp[6], C3 = bp[7];
    float y = 0.f;
    ST4Y(A0, H0, B0, C0); ST4Y(A1, H1, B1, C1);
    ST4Y(A2, H2, B2, C2); ST4Y(A3, H3, B3, C3);
    y = fmaf(De, xbl, y);
    y *= zv / (1.f + __expf(-zv));
    dyp[0] = y;
    dyp += EDx; xp += EDx; bcp += 64; zp += 2 * EDx;
  }
}

// ---------------- last-token LayerNorm + head ----------------
__global__ __launch_bounds__(256) void k_ln_head(
    const float* __restrict__ x, const float* __restrict__ g,
    const float* __restrict__ be, const float* __restrict__ Wo,
    const float* __restrict__ bo, float* __restrict__ out) {
  const int b = blockIdx.x;
  const int t = threadIdx.x;
  const float* xr = x + ((size_t)b * Lx + (Lx - 1)) * DM;
  __shared__ float w1[4], w2[4];
  __shared__ float xn[DM];
  __shared__ float hp[20][8];
  float a0 = xr[t], a1 = xr[t + 256];
  float p = a0 + a1;
  #pragma unroll
  for (int o = 32; o > 0; o >>= 1) p += __shfl_down(p, o);
  if ((t & 63) == 0) w1[t >> 6] = p;
  __syncthreads();
  float mean = (w1[0] + w1[1] + w1[2] + w1[3]) * (1.f / DM);
  float d0 = a0 - mean, d1 = a1 - mean;
  p = d0 * d0 + d1 * d1;
  #pragma unroll
  for (int o = 32; o > 0; o >>= 1) p += __shfl_down(p, o);
  if ((t & 63) == 0) w2[t >> 6] = p;
  __syncthreads();
  float rstd = rsqrtf((w2[0] + w2[1] + w2[2] + w2[3]) * (1.f / DM) + 1e-5f);
  xn[t] = d0 * rstd * g[t] + be[t];
  xn[t + 256] = d1 * rstd * g[t + 256] + be[t + 256];
  __syncthreads();
  if (t < 160) {
    int j = t / 8, sg = t % 8;
    const float* wr = Wo + (size_t)j * DM + sg * 64;
    const float* xs = xn + sg * 64;
    float s = 0.f;
    #pragma unroll
    for (int k = 0; k < 64; ++k) s = fmaf(xs[k], wr[k], s);
    hp[j][sg] = s;
  }
  __syncthreads();
  if (t < 20) {
    float s = bo[t];
    #pragma unroll
    for (int k = 0; k < 8; ++k) s += hp[t][k];
    out[b * 20 + t] = s;
  }
}

extern "C" void kernel_launch(void* const* d_in, const int* in_sizes, int n_in,
                              void* d_out, int out_size, void* d_ws, size_t ws_size,
                              hipStream_t stream) {
  (void)in_sizes; (void)n_in; (void)out_size;
  const float* seq    = (const float*)d_in[0];
  const float* Wi     = (const float*)d_in[1];
  const float* bi     = (const float*)d_in[2];
  const float* Wo     = (const float*)d_in[3];
  const float* bo     = (const float*)d_in[4];
  const float* ln_g   = (const float*)d_in[5];
  const float* ln_b   = (const float*)d_in[6];
  const float* lWin   = (const float*)d_in[7];
  const float* lconvw = (const float*)d_in[8];
  const float* lconvb = (const float*)d_in[9];
  const float* lWx    = (const float*)d_in[10];
  const float* lWdt   = (const float*)d_in[11];
  const float* lbdt   = (const float*)d_in[12];
  const float* lAlog  = (const float*)d_in[13];
  const float* lD     = (const float*)d_in[14];
  const float* lWout  = (const float*)d_in[15];

  float* ws  = (float*)d_ws;
  float* X   = ws;                 // [4096][512]   = 2M floats
  float* XZ  = X + 2097152;        // [4096][2048]  = 8M floats
  float* XB  = XZ + 8388608;       // [4096][1024]  = 4M floats
  float* DBC = XB + 4194304;       // [4096][64]    = 256K floats
  float* DEL = DBC + 262144;       // [4096][1024]  = 4M floats (delta, then y in-place)
  float* PQ  = DEL + 4194304;      // [NC*4096][32] floats; PART aliases (disjoint phase)
  float* PART = PQ;                // [8][4096][64] = 2M floats

  // NC=64 needs 110,100,480 B of ws; fall back to proven NC=32 (93 MB) otherwise.
  const bool big = ws_size >= (size_t)110100480;

  k_init_x<<<dim3(Bx * Lx * DM / 256), 256, 0, stream>>>(seq, Wi, bi, X);

  for (int i = 0; i < NL; ++i) {
    const float* Win  = lWin   + (size_t)i * 2048 * 512;
    const float* cw   = lconvw + (size_t)i * EDx * 4;
    const float* cb   = lconvb + (size_t)i * EDx;
    const float* Wx   = lWx    + (size_t)i * 64 * EDx;
    const float* Wdt  = lWdt   + (size_t)i * EDx * DTR;
    const float* bdt  = lbdt   + (size_t)i * EDx;
    const float* Alog = lAlog  + (size_t)i * EDx * DS;
    const float* Dp   = lD     + (size_t)i * EDx;
    const float* Wout = lWout  + (size_t)i * DM * EDx;

    // xz = x @ Win^T            [4096,2048] K=512   (bf16x3 MFMA)
    k_gemm_mfma<128, 128><<<dim3(32, 16), 256, 0, stream>>>(X, DM, Win, DM, XZ, 2 * EDx, DM);
    // xb = silu(causal_dwconv(xz[:, :ED]) + cb)
    k_conv_silu<<<dim3(Bx * Lx * EDx / 256), 256, 0, stream>>>(XZ, cw, cb, XB);
    // dbc = xb @ Wx^T           [4096,64] K=1024    (bf16x3 MFMA split-K + reduce)
    k_xproj_mfma<8><<<dim3(32, 1, 8), 256, 0, stream>>>(XB, Wx, PART);
    k_redux<8><<<dim3(256), 256, 0, stream>>>(PART, DBC);
    // delta = softplus(dbc[:, :32] @ Wdt^T + bdt)   [4096,1024] K=32
    k_gemm_tn<128, 64, 1><<<dim3(32, 16), 256, 0, stream>>>(DBC, 64, Wdt, DTR, bdt, DEL, EDx, DTR);
    // chunked selective scan + gating, y written over DEL
    if (big) {
      k_scan1<64><<<dim3(4096 * 64 / 256), 256, 0, stream>>>(DEL, XB, DBC, Alog, PQ);
      k_scan2<64><<<dim3(4096 * DS / 256), 256, 0, stream>>>(PQ);
      k_scan3<64><<<dim3(4096 * 64 / 256), 256, 0, stream>>>(DEL, XB, DBC, XZ, Alog, Dp, PQ);
    } else {
      k_scan1<32><<<dim3(4096 * 32 / 256), 256, 0, stream>>>(DEL, XB, DBC, Alog, PQ);
      k_scan2<32><<<dim3(4096 * DS / 256), 256, 0, stream>>>(PQ);
      k_scan3<32><<<dim3(4096 * 32 / 256), 256, 0, stream>>>(DEL, XB, DBC, XZ, Alog, Dp, PQ);
    }
    // x = y @ Wout^T            [4096,512] K=1024   (bf16x3 MFMA)
    k_gemm_mfma<128, 64><<<dim3(32, 8), 256, 0, stream>>>(DEL, EDx, Wout, EDx, X, DM, EDx);
  }

  k_ln_head<<<dim3(Bx), 256, 0, stream>>>(X, ln_g, ln_b, Wo, bo, (float*)d_out);
}